// Round 7
// baseline (225.171 us; speedup 1.0000x reference)
//
#include <hip/hip_runtime.h>
#include <math.h>

#define S_LEN 1024
#define D_MOD 512
#define NH 8
#define DK 64
#define NB 8

typedef __attribute__((ext_vector_type(8))) short short8;   // 8 bf16 in 4 VGPRs
typedef __attribute__((ext_vector_type(4))) float floatx4;  // MFMA accumulator

typedef __attribute__((address_space(1))) const void* gas_ptr;
typedef __attribute__((address_space(3))) void* las_ptr;

union U8 { ushort u[8]; short8 v; };

__device__ __forceinline__ ushort f2bf(float x) {
  unsigned u = __float_as_uint(x);
  unsigned r = (u + 0x7fffu + ((u >> 16) & 1u)) >> 16;  // RNE
  return (ushort)r;
}

// 16B direct global->LDS (DMA, no VGPR round-trip). LDS dest semantics:
// wave-uniform base + lane*16 (m104/m108). Global source is per-lane.
__device__ __forceinline__ void gload16(const ushort* g, char* l) {
  __builtin_amdgcn_global_load_lds((gas_ptr)g, (las_ptr)l, 16, 0, 0);
}

// ---------------------------------------------------------------------------
// Fused prep: y=0..2 -> fp32->bf16 convert of q/k/v; y=3 -> mask bit-pack;
// y=4 (x<192) -> weight transpose+convert.
// ---------------------------------------------------------------------------
__global__ __launch_bounds__(256) void prep_kern(
    const float* __restrict__ q, const float* __restrict__ k,
    const float* __restrict__ v, const int* __restrict__ smask,
    const float* __restrict__ W0, const float* __restrict__ W1,
    const float* __restrict__ W2,
    ushort* __restrict__ qo, ushort* __restrict__ ko,
    ushort* __restrict__ vo, unsigned long long* __restrict__ mb,
    ushort* __restrict__ T0, ushort* __restrict__ T1, ushort* __restrict__ T2)
{
  __shared__ __align__(16) ushort tile[64][72];   // used by y==4 path only
  const int y = blockIdx.y;
  const int t = threadIdx.x;
  if (y < 3) {
    const float* src = (y == 0) ? q : (y == 1) ? k : v;
    ushort* dst = (y == 0) ? qo : (y == 1) ? ko : vo;
    const int i = blockIdx.x * 256 + t;
    const float4 a = *((const float4*)src + i * 2);
    const float4 b = *((const float4*)src + i * 2 + 1);
    U8 o;
    o.u[0] = f2bf(a.x); o.u[1] = f2bf(a.y); o.u[2] = f2bf(a.z); o.u[3] = f2bf(a.w);
    o.u[4] = f2bf(b.x); o.u[5] = f2bf(b.y); o.u[6] = f2bf(b.z); o.u[7] = f2bf(b.w);
    *(short8*)(dst + (size_t)i * 8) = o.v;
  } else if (y == 3) {
    const int row = blockIdx.x * 4 + (t >> 6);
    const int lane = t & 63;
    const int* p = smask + (size_t)row * S_LEN;
    unsigned long long mine = 0;
#pragma unroll
    for (int r = 0; r < 16; ++r) {
      int m = p[r * 64 + lane];
      unsigned long long w = __ballot(m != 0);
      if (lane == r) mine = w;
    }
    if (lane < 16) mb[(size_t)row * 16 + lane] = mine;
  } else {
    const int j = blockIdx.x;
    if (j >= 192) return;
    const int z = j >> 6;
    const int rem = j & 63;
    const int n0 = (rem >> 3) * 64;
    const int k0 = (rem & 7) * 64;
    const float* W = (z == 0) ? W0 : (z == 1) ? W1 : W2;
    ushort* Wt = (z == 0) ? T0 : (z == 1) ? T1 : T2;
    {
      const int r = t >> 2;
      const int c0 = (t & 3) * 16;
      const float* p = &W[(size_t)(k0 + r) * 512 + n0 + c0];
#pragma unroll
      for (int jj = 0; jj < 16; ++jj) tile[r][c0 + jj] = f2bf(p[jj]);
    }
    __syncthreads();
    {
      const int c = t >> 2;
      const int kg = (t & 3) * 16;
      U8 lo, hi;
#pragma unroll
      for (int jj = 0; jj < 8; ++jj) lo.u[jj] = tile[kg + jj][c];
#pragma unroll
      for (int jj = 0; jj < 8; ++jj) hi.u[jj] = tile[kg + 8 + jj][c];
      ushort* qq = &Wt[(size_t)(n0 + c) * 512 + k0 + kg];
      *(short8*)qq = lo.v;
      *(short8*)(qq + 8) = hi.v;
    }
  }
}

// ---------------------------------------------------------------------------
// bf16 MFMA GEMM, 128m x 128n block. B-tile staged via global_load_lds
// width=16 (linear LDS dest, PRE-SWIZZLED global source chunk). Double-
// buffered, 1 barrier/iter. A wave-private reg ring depth-2. (R6; kept
// frozen in R7 for a clean attn A/B.)
// z=0/1: bf16 row-major out. z=2: Vt [B,H,64,S].
// ---------------------------------------------------------------------------
__global__ __launch_bounds__(256) void gemm_qkv_kern(
    const ushort* __restrict__ qr, const ushort* __restrict__ kr,
    const ushort* __restrict__ vr, const ushort* __restrict__ Wqt,
    const ushort* __restrict__ Wvt, const float* __restrict__ bq,
    const float* __restrict__ bv, ushort* __restrict__ Qo,
    ushort* __restrict__ Ko, ushort* __restrict__ VtO)
{
  __shared__ __align__(16) ushort Bl[2][128][64];  // 32 KB

  const int z = blockIdx.z;
  const ushort* A = (z == 0) ? qr : (z == 1) ? kr : vr;
  const ushort* Wt = (z == 2) ? Wvt : Wqt;
  const float* bias = (z == 2) ? bv : bq;

  const int t = threadIdx.x;
  const int w = t >> 6;
  const int lane = t & 63;
  const int quad = lane >> 4;
  const int i16 = lane & 15;
  const int mbase = blockIdx.x * 128 + w * 32;
  const int nbase = blockIdx.y * 128;
  const int xb = i16 & 7;

  const int srow = t >> 3;                 // row within 32-row group
  const int lcg = (t & 7) ^ (srow & 7);    // source logical chunk
  const ushort* Bsrc = Wt + (size_t)(nbase + srow) * 512 + lcg * 8;
  char* const lw = (char*)&Bl[0][0][0] + w * 1024;   // wave base, buffer 0

  const ushort* Ap = A + (size_t)(mbase + i16) * 512 + quad * 8;

  floatx4 acc[2][8];
#pragma unroll
  for (int mi = 0; mi < 2; ++mi)
#pragma unroll
    for (int ni = 0; ni < 8; ++ni) acc[mi][ni] = (floatx4)(0.f);

  short8 areg[2][2][2];  // ring, mi, kc
#pragma unroll
  for (int mi = 0; mi < 2; ++mi)
#pragma unroll
    for (int kc = 0; kc < 2; ++kc)
      areg[0][mi][kc] = *(const short8*)(Ap + kc * 32 + mi * 16 * 512);

#pragma unroll
  for (int c = 0; c < 4; ++c)
    gload16(Bsrc + (size_t)c * 16384, lw + c * 4096);
  __syncthreads();

#pragma unroll
  for (int kt = 0; kt < 8; ++kt) {
    const int cb = kt & 1;
    if (kt < 7) {
#pragma unroll
      for (int c = 0; c < 4; ++c)
        gload16(Bsrc + (size_t)c * 16384 + (kt + 1) * 64,
                lw + (cb ^ 1) * 16384 + c * 4096);
#pragma unroll
      for (int mi = 0; mi < 2; ++mi)
#pragma unroll
        for (int kc = 0; kc < 2; ++kc)
          areg[(kt + 1) & 1][mi][kc] =
              *(const short8*)(Ap + (kt + 1) * 64 + kc * 32 + mi * 16 * 512);
    }
#pragma unroll
    for (int kc = 0; kc < 2; ++kc) {
      short8 bf8[8];
#pragma unroll
      for (int ni = 0; ni < 8; ++ni)
        bf8[ni] = *(const short8*)&Bl[cb][ni * 16 + i16][((kc * 4 + quad) ^ xb) * 8];
#pragma unroll
      for (int mi = 0; mi < 2; ++mi)
#pragma unroll
        for (int ni = 0; ni < 8; ++ni)
          acc[mi][ni] = __builtin_amdgcn_mfma_f32_16x16x32_bf16(
              areg[kt & 1][mi][kc], bf8[ni], acc[mi][ni], 0, 0, 0);
    }
    if (kt < 7) __syncthreads();   // implicit vmcnt(0) drains gload_lds
  }

  float bv8[8];
#pragma unroll
  for (int ni = 0; ni < 8; ++ni) bv8[ni] = bias[nbase + ni * 16 + i16];

  if (z < 2) {
    ushort* C = (z == 0) ? Qo : Ko;
#pragma unroll
    for (int mi = 0; mi < 2; ++mi)
#pragma unroll
      for (int ni = 0; ni < 8; ++ni)
#pragma unroll
        for (int r = 0; r < 4; ++r) {
          const int m = mbase + mi * 16 + quad * 4 + r;
          const int n = nbase + ni * 16 + i16;
          C[(size_t)m * 512 + n] = f2bf(acc[mi][ni][r] + bv8[ni]);
        }
  } else {
#pragma unroll
    for (int mi = 0; mi < 2; ++mi)
#pragma unroll
      for (int ni = 0; ni < 8; ++ni) {
        const int m = mbase + mi * 16 + quad * 4;
        const int b = m >> 10;
        const int s = m & 1023;
        const int n = nbase + ni * 16 + i16;
        const int h = n >> 6;
        const int c = n & 63;
        ushort4 pk;
        pk.x = f2bf(acc[mi][ni][0] + bv8[ni]);
        pk.y = f2bf(acc[mi][ni][1] + bv8[ni]);
        pk.z = f2bf(acc[mi][ni][2] + bv8[ni]);
        pk.w = f2bf(acc[mi][ni][3] + bv8[ni]);
        *(ushort4*)(VtO + (((size_t)b * NH + h) * DK + c) * S_LEN + s) = pk;
      }
  }
}

// ---------------------------------------------------------------------------
// Output GEMM: X = Obf @ Wot^T + bo + R (fp32 out). 128x128 tile,
// gload_lds staging (same pattern as gemm_qkv). Frozen from R6.
// ---------------------------------------------------------------------------
__global__ __launch_bounds__(256) void gemm_out_kern(
    const ushort* __restrict__ A, const ushort* __restrict__ Wt,
    const float* __restrict__ bias, const float* __restrict__ R,
    float* __restrict__ X)
{
  __shared__ __align__(16) ushort Bl[2][128][64];  // 32 KB

  const int t = threadIdx.x;
  const int w = t >> 6;
  const int lane = t & 63;
  const int quad = lane >> 4;
  const int i16 = lane & 15;
  const int mbase = blockIdx.x * 128 + w * 32;
  const int nbase = blockIdx.y * 128;
  const int xb = i16 & 7;

  const int srow = t >> 3;
  const int lcg = (t & 7) ^ (srow & 7);
  const ushort* Bsrc = Wt + (size_t)(nbase + srow) * 512 + lcg * 8;
  char* const lw = (char*)&Bl[0][0][0] + w * 1024;

  const ushort* Ap = A + (size_t)(mbase + i16) * 512 + quad * 8;

  floatx4 acc[2][8];
#pragma unroll
  for (int mi = 0; mi < 2; ++mi)
#pragma unroll
    for (int ni = 0; ni < 8; ++ni) acc[mi][ni] = (floatx4)(0.f);

  short8 areg[2][2][2];
#pragma unroll
  for (int mi = 0; mi < 2; ++mi)
#pragma unroll
    for (int kc = 0; kc < 2; ++kc)
      areg[0][mi][kc] = *(const short8*)(Ap + kc * 32 + mi * 16 * 512);

#pragma unroll
  for (int c = 0; c < 4; ++c)
    gload16(Bsrc + (size_t)c * 16384, lw + c * 4096);
  __syncthreads();

#pragma unroll
  for (int kt = 0; kt < 8; ++kt) {
    const int cb = kt & 1;
    if (kt < 7) {
#pragma unroll
      for (int c = 0; c < 4; ++c)
        gload16(Bsrc + (size_t)c * 16384 + (kt + 1) * 64,
                lw + (cb ^ 1) * 16384 + c * 4096);
#pragma unroll
      for (int mi = 0; mi < 2; ++mi)
#pragma unroll
        for (int kc = 0; kc < 2; ++kc)
          areg[(kt + 1) & 1][mi][kc] =
              *(const short8*)(Ap + (kt + 1) * 64 + kc * 32 + mi * 16 * 512);
    }
#pragma unroll
    for (int kc = 0; kc < 2; ++kc) {
      short8 bf8[8];
#pragma unroll
      for (int ni = 0; ni < 8; ++ni)
        bf8[ni] = *(const short8*)&Bl[cb][ni * 16 + i16][((kc * 4 + quad) ^ xb) * 8];
#pragma unroll
      for (int mi = 0; mi < 2; ++mi)
#pragma unroll
        for (int ni = 0; ni < 8; ++ni)
          acc[mi][ni] = __builtin_amdgcn_mfma_f32_16x16x32_bf16(
              areg[kt & 1][mi][kc], bf8[ni], acc[mi][ni], 0, 0, 0);
    }
    if (kt < 7) __syncthreads();
  }

  float bv8[8];
#pragma unroll
  for (int ni = 0; ni < 8; ++ni) bv8[ni] = bias[nbase + ni * 16 + i16];
#pragma unroll
  for (int mi = 0; mi < 2; ++mi)
#pragma unroll
    for (int ni = 0; ni < 8; ++ni)
#pragma unroll
      for (int r = 0; r < 4; ++r) {
        const int m = mbase + mi * 16 + quad * 4 + r;
        const int n = nbase + ni * 16 + i16;
        X[(size_t)m * 512 + n] = acc[mi][ni][r] + bv8[ni] + R[(size_t)m * 512 + n];
      }
}

// ---------------------------------------------------------------------------
// MFMA dual-score causal attention. R7: K/Kr/V staging via global_load_lds
// width=16 (DMA direct to LDS), pre-swizzled source chunk lcs=(t&7)^(rr&7)
// so the swizzled physical layout (and all read-side code) is bit-identical
// to R3. Removes 6 ds_write_b128 + 24 prefetch VGPRs + staging addr VALU
// per iter. Double-buffered, 1 barrier/iter (barrier's implicit vmcnt(0)
// drains the DMA; it also fences buffer reuse exactly as the old ds_writes).
// Seg-paired (p, 15-p) -> 17 iters/block, 4 waves, 256 threads.
// ---------------------------------------------------------------------------
__global__ __launch_bounds__(256) void attn_kern(
    const ushort* __restrict__ Qb, const ushort* __restrict__ Kb,
    const ushort* __restrict__ VtG, const ushort* __restrict__ qraw,
    const ushort* __restrict__ kraw,
    const unsigned long long* __restrict__ mbits,
    const float* __restrict__ gammas, ushort* __restrict__ Obf)
{
  __shared__ __align__(16) ushort Kp[2][64][64];
  __shared__ __align__(16) ushort Kr[2][64][64];
  __shared__ __align__(16) ushort Vc[2][64][64];
  __shared__ __align__(16) ushort Pl[4][16][64];

  const int t = threadIdx.x;
  const int w = t >> 6;
  const int lane = t & 63;
  const int quad = lane >> 4;
  const int i16 = lane & 15;
  const int bh = blockIdx.x;          // 0..63
  const int b = bh >> 3;
  const int h = bh & 7;
  const int p = blockIdx.y;           // 0..7

  const float gam = gammas[h];
  float te = __expf(-log1pf(__expf(gam)));
  te = fminf(fmaxf(te, 1e-5f), 1e5f);
  const float c1 = 0.125f * 1.44269504f;
  const float c2 = te * 0.044194173824159216f * 1.44269504f;

  const int xi = i16 & 7;
  const int rr = t >> 3;                  // staging row 0..31 (w*8 + lane>>3)
  const int lcs = (t & 7) ^ (rr & 7);     // pre-swizzled source chunk

  const ushort* kpgB = Kb + ((size_t)b * S_LEN + rr) * D_MOD + h * DK + lcs * 8;
  const ushort* krgB = kraw + ((size_t)b * S_LEN + rr) * D_MOD + h * DK + lcs * 8;
  const ushort* vgB  = VtG + ((size_t)bh * DK + rr) * S_LEN + lcs * 8;

  // wave-uniform LDS dest bases (lane*16 implicit): rows w*8..w*8+7 (+32)
  const int wr = w * 8;

#pragma unroll
  for (int seg = 0; seg < 2; ++seg) {
    const int qt = seg ? (15 - p) : p;
    const int qbase = qt * 64 + w * 16;

    short8 Qp[2], Qr[2];
    {
      const ushort* qp = Qb + ((size_t)b * S_LEN + qbase + i16) * D_MOD + h * DK + quad * 8;
      const ushort* qq = qraw + ((size_t)b * S_LEN + qbase + i16) * D_MOD + h * DK + quad * 8;
#pragma unroll
      for (int s = 0; s < 2; ++s) {
        Qp[s] = *(const short8*)(qp + s * 32);
        Qr[s] = *(const short8*)(qq + s * 32);
      }
    }

    floatx4 Oacc[4];
#pragma unroll
    for (int t4 = 0; t4 < 4; ++t4) Oacc[t4] = (floatx4)(0.f);
    float l_run[4] = {0.f, 0.f, 0.f, 0.f};

    const int nit = qt + 1;

    // ---- prologue: DMA tile 0 into buffer 0 ----
    __syncthreads();   // prior seg's readers done before overwrite
    gload16(kpgB, (char*)&Kp[0][wr][0]);
    gload16(kpgB + 32 * D_MOD, (char*)&Kp[0][32 + wr][0]);
    gload16(krgB, (char*)&Kr[0][wr][0]);
    gload16(krgB + 32 * D_MOD, (char*)&Kr[0][32 + wr][0]);
    gload16(vgB, (char*)&Vc[0][wr][0]);
    gload16(vgB + 32 * S_LEN, (char*)&Vc[0][32 + wr][0]);
    __syncthreads();   // vmcnt(0): tile 0 landed

    for (int kt = 0; kt < nit; ++kt) {
      const int cb = kt & 1;
      const int nb = cb ^ 1;
      const bool havenext = (kt + 1 < nit);
      const bool diag = (kt == qt);

      // ---- DMA next tile into the other buffer; lands during compute ----
      if (havenext) {
        const size_t ko = (size_t)(kt + 1) * 64;
        gload16(kpgB + ko * D_MOD, (char*)&Kp[nb][wr][0]);
        gload16(kpgB + ko * D_MOD + 32 * D_MOD, (char*)&Kp[nb][32 + wr][0]);
        gload16(krgB + ko * D_MOD, (char*)&Kr[nb][wr][0]);
        gload16(krgB + ko * D_MOD + 32 * D_MOD, (char*)&Kr[nb][32 + wr][0]);
        gload16(vgB + ko, (char*)&Vc[nb][wr][0]);
        gload16(vgB + ko + 32 * S_LEN, (char*)&Vc[nb][32 + wr][0]);
      }

      unsigned long long mw[4];
#pragma unroll
      for (int r = 0; r < 4; ++r)
        mw[r] = mbits[((size_t)b * S_LEN + qbase + quad * 4 + r) * 16 + kt];

      // ---- scores: 16 MFMAs from LDS ----
      floatx4 accp[4], accr[4];
#pragma unroll
      for (int t4 = 0; t4 < 4; ++t4) { accp[t4] = (floatx4)(0.f); accr[t4] = (floatx4)(0.f); }
#pragma unroll
      for (int s = 0; s < 2; ++s) {
        const int co = ((s * 4 + quad) ^ xi) * 8;
        short8 kp4[4], kr4[4];
#pragma unroll
        for (int t4 = 0; t4 < 4; ++t4) kp4[t4] = *(const short8*)&Kp[cb][t4 * 16 + i16][co];
#pragma unroll
        for (int t4 = 0; t4 < 4; ++t4) kr4[t4] = *(const short8*)&Kr[cb][t4 * 16 + i16][co];
#pragma unroll
        for (int t4 = 0; t4 < 4; ++t4)
          accp[t4] = __builtin_amdgcn_mfma_f32_16x16x32_bf16(Qp[s], kp4[t4], accp[t4], 0, 0, 0);
#pragma unroll
        for (int t4 = 0; t4 < 4; ++t4)
          accr[t4] = __builtin_amdgcn_mfma_f32_16x16x32_bf16(Qr[s], kr4[t4], accr[t4], 0, 0, 0);
      }

      // ---- combine + exp2, P -> per-wave LDS (truncation pack) ----
      const int k0g = kt * 64;
#pragma unroll
      for (int r = 0; r < 4; ++r) {
        const int qg = qbase + quad * 4 + r;
        const int prow = quad * 4 + r;
#pragma unroll
        for (int t4 = 0; t4 < 4; ++t4) {
          const float bitf = ((mw[r] >> (t4 * 16 + i16)) & 1ULL) ? c2 : 0.f;
          const float sv = accp[t4][r] * c1 + accr[t4][r] * bitf;
          float pv = __builtin_amdgcn_exp2f(sv);
          if (diag) {
            const int kg = k0g + t4 * 16 + i16;
            pv = (kg < qg) ? pv : 0.f;
          }
          l_run[r] += pv;
          const int kc = t4 * 2 + (i16 >> 3);
          Pl[w][prow][((kc ^ (prow & 7)) * 8) + (i16 & 7)] =
              (ushort)(__float_as_uint(pv) >> 16);
        }
      }

      // ---- PV: 8 MFMAs ----
#pragma unroll
      for (int s = 0; s < 2; ++s) {
        const int co = ((s * 4 + quad) ^ xi) * 8;
        short8 a = *(const short8*)&Pl[w][i16][co];
#pragma unroll
        for (int t4 = 0; t4 < 4; ++t4) {
          short8 bv8 = *(const short8*)&Vc[cb][t4 * 16 + i16][co];
          Oacc[t4] = __builtin_amdgcn_mfma_f32_16x16x32_bf16(a, bv8, Oacc[t4], 0, 0, 0);
        }
      }

      // ---- barrier: drains next-tile DMA, fences buffer reuse ----
      if (havenext) __syncthreads();
    }

    // ---- epilogue ----
#pragma unroll
    for (int r = 0; r < 4; ++r) {
      float l = l_run[r];
#pragma unroll
      for (int off = 1; off < 16; off <<= 1) l += __shfl_xor(l, off);
      const float inv = (l > 0.f) ? 1.f / l : 0.f;
      ushort* orow = Obf + ((size_t)b * S_LEN + qbase + quad * 4 + r) * D_MOD + h * DK;
#pragma unroll
      for (int t4 = 0; t4 < 4; ++t4)
        orow[t4 * 16 + i16] = f2bf(Oacc[t4][r] * inv);
    }
  }
}

// ---------------------------------------------------------------------------
// LayerNorm over D=512, one wave per row.
// ---------------------------------------------------------------------------
__global__ __launch_bounds__(256) void ln_kern(
    const float* __restrict__ X, const float* __restrict__ gw,
    const float* __restrict__ bw, float* __restrict__ out)
{
  const int row = blockIdx.x * 4 + (threadIdx.x >> 6);
  const int lane = threadIdx.x & 63;
  const int c = lane * 8;
  const float* xp = &X[(size_t)row * D_MOD + c];
  const float4 x0 = *(const float4*)xp;
  const float4 x1 = *(const float4*)(xp + 4);
  float xv[8] = {x0.x, x0.y, x0.z, x0.w, x1.x, x1.y, x1.z, x1.w};
  float sum = 0.f;
#pragma unroll
  for (int u = 0; u < 8; ++u) sum += xv[u];
#pragma unroll
  for (int off = 1; off < 64; off <<= 1) sum += __shfl_xor(sum, off, 64);
  const float mu = sum * (1.f / 512.f);
  float ss = 0.f;
#pragma unroll
  for (int u = 0; u < 8; ++u) { xv[u] -= mu; ss += xv[u] * xv[u]; }
#pragma unroll
  for (int off = 1; off < 64; off <<= 1) ss += __shfl_xor(ss, off, 64);
  const float rstd = rsqrtf(ss * (1.f / 512.f) + 1e-5f);
  const float4 g0 = *(const float4*)&gw[c];
  const float4 g1 = *(const float4*)&gw[c + 4];
  const float4 b0 = *(const float4*)&bw[c];
  const float4 b1 = *(const float4*)&bw[c + 4];
  float* op = &out[(size_t)row * D_MOD + c];
  *(float4*)op = make_float4(xv[0] * rstd * g0.x + b0.x,
                             xv[1] * rstd * g0.y + b0.y,
                             xv[2] * rstd * g0.z + b0.z,
                             xv[3] * rstd * g0.w + b0.w);
  *(float4*)(op + 4) = make_float4(xv[4] * rstd * g1.x + b1.x,
                                   xv[5] * rstd * g1.y + b1.y,
                                   xv[6] * rstd * g1.z + b1.z,
                                   xv[7] * rstd * g1.w + b1.w);
}

// ---------------------------------------------------------------------------
extern "C" void kernel_launch(void* const* d_in, const int* in_sizes, int n_in,
                              void* d_out, int out_size, void* d_ws, size_t ws_size,
                              hipStream_t stream)
{
  const float* q_in  = (const float*)d_in[0];
  const float* k_in  = (const float*)d_in[1];
  const float* v_in  = (const float*)d_in[2];
  const int*   smask = (const int*)d_in[3];
  const float* Wq = (const float*)d_in[4];
  const float* bq = (const float*)d_in[5];
  const float* Wv = (const float*)d_in[6];
  const float* bv = (const float*)d_in[7];
  const float* Wo = (const float*)d_in[8];
  const float* bo = (const float*)d_in[9];
  const float* gammas = (const float*)d_in[10];
  const float* ln_g = (const float*)d_in[11];
  const float* ln_b = (const float*)d_in[12];
  float* out = (float*)d_out;

  char* ws = (char*)d_ws;
  const size_t BF = (size_t)NB * S_LEN * D_MOD * sizeof(ushort);  // 8 MiB
  ushort* qr  = (ushort*)(ws);                 // [0,8M)
  ushort* kr  = (ushort*)(ws + BF);            // [8M,16M)
  ushort* vr  = (ushort*)(ws + 2 * BF);        // [16M,24M); Obf overlays after V-GEMM
  ushort* Obf = (ushort*)(ws + 2 * BF);
  ushort* Qbf = (ushort*)(ws + 3 * BF);        // [24M,32M)
  ushort* Kbf = (ushort*)(ws + 4 * BF);        // [32M,40M)
  ushort* Vt  = (ushort*)(ws + 5 * BF);        // [40M,48M)
  unsigned long long* mbits = (unsigned long long*)(ws + 6 * BF);      // 1 MiB
  ushort* Wqt = (ushort*)(ws + 6 * BF + (1 << 20));                    // 512 KiB
  ushort* Wvt = Wqt + 512 * 512;
  ushort* Wot = Wvt + 512 * 512;
  float*  X   = (float*)ws;                    // overlays qr+kr (dead after attn)

  const dim3 tb(256);

  prep_kern<<<dim3(2048, 5), tb, 0, stream>>>(q_in, k_in, v_in, smask,
                                              Wq, Wv, Wo,
                                              qr, kr, vr, mbits,
                                              Wqt, Wvt, Wot);

  gemm_qkv_kern<<<dim3(64, 4, 3), tb, 0, stream>>>(qr, kr, vr, Wqt, Wvt,
                                                   bq, bv, Qbf, Kbf, Vt);

  attn_kern<<<dim3(64, 8), tb, 0, stream>>>(Qbf, Kbf, Vt, qr, kr, mbits,
                                            gammas, Obf);

  gemm_out_kern<<<dim3(64, 4), tb, 0, stream>>>(Obf, Wot, bo, q_in, X);
  ln_kern<<<2048, tb, 0, stream>>>(X, ln_g, ln_b, out);
}

// Round 9
// 220.543 us; speedup vs baseline: 1.0210x; 1.0210x over previous
//
#include <hip/hip_runtime.h>
#include <math.h>

#define S_LEN 1024
#define D_MOD 512
#define NH 8
#define DK 64
#define NB 8

typedef __attribute__((ext_vector_type(8))) short short8;   // 8 bf16 in 4 VGPRs
typedef __attribute__((ext_vector_type(4))) float floatx4;  // MFMA accumulator

typedef __attribute__((address_space(1))) const void* gas_ptr;
typedef __attribute__((address_space(3))) void* las_ptr;

union U8 { ushort u[8]; short8 v; };

__device__ __forceinline__ ushort f2bf(float x) {
  unsigned u = __float_as_uint(x);
  unsigned r = (u + 0x7fffu + ((u >> 16) & 1u)) >> 16;  // RNE
  return (ushort)r;
}

// 16B direct global->LDS (DMA, no VGPR round-trip). LDS dest semantics:
// wave-uniform base + lane*16 (m104/m108). Global source is per-lane.
__device__ __forceinline__ void gload16(const ushort* g, char* l) {
  __builtin_amdgcn_global_load_lds((gas_ptr)g, (las_ptr)l, 16, 0, 0);
}

// ---------------------------------------------------------------------------
// Fused prep: y=0..2 -> fp32->bf16 convert of q/k/v; y=3 -> mask bit-pack;
// y=4 (x<192) -> weight transpose+convert.
// ---------------------------------------------------------------------------
__global__ __launch_bounds__(256) void prep_kern(
    const float* __restrict__ q, const float* __restrict__ k,
    const float* __restrict__ v, const int* __restrict__ smask,
    const float* __restrict__ W0, const float* __restrict__ W1,
    const float* __restrict__ W2,
    ushort* __restrict__ qo, ushort* __restrict__ ko,
    ushort* __restrict__ vo, unsigned long long* __restrict__ mb,
    ushort* __restrict__ T0, ushort* __restrict__ T1, ushort* __restrict__ T2)
{
  __shared__ __align__(16) ushort tile[64][72];   // used by y==4 path only
  const int y = blockIdx.y;
  const int t = threadIdx.x;
  if (y < 3) {
    const float* src = (y == 0) ? q : (y == 1) ? k : v;
    ushort* dst = (y == 0) ? qo : (y == 1) ? ko : vo;
    const int i = blockIdx.x * 256 + t;
    const float4 a = *((const float4*)src + i * 2);
    const float4 b = *((const float4*)src + i * 2 + 1);
    U8 o;
    o.u[0] = f2bf(a.x); o.u[1] = f2bf(a.y); o.u[2] = f2bf(a.z); o.u[3] = f2bf(a.w);
    o.u[4] = f2bf(b.x); o.u[5] = f2bf(b.y); o.u[6] = f2bf(b.z); o.u[7] = f2bf(b.w);
    *(short8*)(dst + (size_t)i * 8) = o.v;
  } else if (y == 3) {
    const int row = blockIdx.x * 4 + (t >> 6);
    const int lane = t & 63;
    const int* p = smask + (size_t)row * S_LEN;
    unsigned long long mine = 0;
#pragma unroll
    for (int r = 0; r < 16; ++r) {
      int m = p[r * 64 + lane];
      unsigned long long w = __ballot(m != 0);
      if (lane == r) mine = w;
    }
    if (lane < 16) mb[(size_t)row * 16 + lane] = mine;
  } else {
    const int j = blockIdx.x;
    if (j >= 192) return;
    const int z = j >> 6;
    const int rem = j & 63;
    const int n0 = (rem >> 3) * 64;
    const int k0 = (rem & 7) * 64;
    const float* W = (z == 0) ? W0 : (z == 1) ? W1 : W2;
    ushort* Wt = (z == 0) ? T0 : (z == 1) ? T1 : T2;
    {
      const int r = t >> 2;
      const int c0 = (t & 3) * 16;
      const float* p = &W[(size_t)(k0 + r) * 512 + n0 + c0];
#pragma unroll
      for (int jj = 0; jj < 16; ++jj) tile[r][c0 + jj] = f2bf(p[jj]);
    }
    __syncthreads();
    {
      const int c = t >> 2;
      const int kg = (t & 3) * 16;
      U8 lo, hi;
#pragma unroll
      for (int jj = 0; jj < 8; ++jj) lo.u[jj] = tile[kg + jj][c];
#pragma unroll
      for (int jj = 0; jj < 8; ++jj) hi.u[jj] = tile[kg + 8 + jj][c];
      ushort* qq = &Wt[(size_t)(n0 + c) * 512 + k0 + kg];
      *(short8*)qq = lo.v;
      *(short8*)(qq + 8) = hi.v;
    }
  }
}

// ---------------------------------------------------------------------------
// bf16 MFMA GEMM, 128m x 128n block. B-tile staged via global_load_lds
// width=16 (linear LDS dest, PRE-SWIZZLED global source chunk). Double-
// buffered, 1 barrier/iter. A wave-private reg ring depth-2.
// R8: z==0 (Q) output pre-scaled by c1 = 0.125*log2e — attn's QK^T score
// then needs no per-element scale (MFMA linear in A; Qbf consumed only by
// attn). z=0/1: bf16 row-major out. z=2: Vt [B,H,64,S].
// ---------------------------------------------------------------------------
__global__ __launch_bounds__(256) void gemm_qkv_kern(
    const ushort* __restrict__ qr, const ushort* __restrict__ kr,
    const ushort* __restrict__ vr, const ushort* __restrict__ Wqt,
    const ushort* __restrict__ Wvt, const float* __restrict__ bq,
    const float* __restrict__ bv, ushort* __restrict__ Qo,
    ushort* __restrict__ Ko, ushort* __restrict__ VtO)
{
  __shared__ __align__(16) ushort Bl[2][128][64];  // 32 KB

  const int z = blockIdx.z;
  const ushort* A = (z == 0) ? qr : (z == 1) ? kr : vr;
  const ushort* Wt = (z == 2) ? Wvt : Wqt;
  const float* bias = (z == 2) ? bv : bq;

  const int t = threadIdx.x;
  const int w = t >> 6;
  const int lane = t & 63;
  const int quad = lane >> 4;
  const int i16 = lane & 15;
  const int mbase = blockIdx.x * 128 + w * 32;
  const int nbase = blockIdx.y * 128;
  const int xb = i16 & 7;

  const int srow = t >> 3;                 // row within 32-row group
  const int lcg = (t & 7) ^ (srow & 7);    // source logical chunk
  const ushort* Bsrc = Wt + (size_t)(nbase + srow) * 512 + lcg * 8;
  char* const lw = (char*)&Bl[0][0][0] + w * 1024;   // wave base, buffer 0

  const ushort* Ap = A + (size_t)(mbase + i16) * 512 + quad * 8;

  floatx4 acc[2][8];
#pragma unroll
  for (int mi = 0; mi < 2; ++mi)
#pragma unroll
    for (int ni = 0; ni < 8; ++ni) acc[mi][ni] = (floatx4)(0.f);

  short8 areg[2][2][2];  // ring, mi, kc
#pragma unroll
  for (int mi = 0; mi < 2; ++mi)
#pragma unroll
    for (int kc = 0; kc < 2; ++kc)
      areg[0][mi][kc] = *(const short8*)(Ap + kc * 32 + mi * 16 * 512);

#pragma unroll
  for (int c = 0; c < 4; ++c)
    gload16(Bsrc + (size_t)c * 16384, lw + c * 4096);
  __syncthreads();

#pragma unroll
  for (int kt = 0; kt < 8; ++kt) {
    const int cb = kt & 1;
    if (kt < 7) {
#pragma unroll
      for (int c = 0; c < 4; ++c)
        gload16(Bsrc + (size_t)c * 16384 + (kt + 1) * 64,
                lw + (cb ^ 1) * 16384 + c * 4096);
#pragma unroll
      for (int mi = 0; mi < 2; ++mi)
#pragma unroll
        for (int kc = 0; kc < 2; ++kc)
          areg[(kt + 1) & 1][mi][kc] =
              *(const short8*)(Ap + (kt + 1) * 64 + kc * 32 + mi * 16 * 512);
    }
#pragma unroll
    for (int kc = 0; kc < 2; ++kc) {
      short8 bf8[8];
#pragma unroll
      for (int ni = 0; ni < 8; ++ni)
        bf8[ni] = *(const short8*)&Bl[cb][ni * 16 + i16][((kc * 4 + quad) ^ xb) * 8];
#pragma unroll
      for (int mi = 0; mi < 2; ++mi)
#pragma unroll
        for (int ni = 0; ni < 8; ++ni)
          acc[mi][ni] = __builtin_amdgcn_mfma_f32_16x16x32_bf16(
              areg[kt & 1][mi][kc], bf8[ni], acc[mi][ni], 0, 0, 0);
    }
    if (kt < 7) __syncthreads();   // implicit vmcnt(0) drains gload_lds
  }

  float bv8[8];
#pragma unroll
  for (int ni = 0; ni < 8; ++ni) bv8[ni] = bias[nbase + ni * 16 + i16];

  if (z < 2) {
    // z==0: bake c1 = 0.125 * log2(e) into Q so attn skips the score scale.
    const float osc = (z == 0) ? 0.18033688f : 1.0f;
    ushort* C = (z == 0) ? Qo : Ko;
#pragma unroll
    for (int mi = 0; mi < 2; ++mi)
#pragma unroll
      for (int ni = 0; ni < 8; ++ni)
#pragma unroll
        for (int r = 0; r < 4; ++r) {
          const int m = mbase + mi * 16 + quad * 4 + r;
          const int n = nbase + ni * 16 + i16;
          C[(size_t)m * 512 + n] = f2bf((acc[mi][ni][r] + bv8[ni]) * osc);
        }
  } else {
#pragma unroll
    for (int mi = 0; mi < 2; ++mi)
#pragma unroll
      for (int ni = 0; ni < 8; ++ni) {
        const int m = mbase + mi * 16 + quad * 4;
        const int b = m >> 10;
        const int s = m & 1023;
        const int n = nbase + ni * 16 + i16;
        const int h = n >> 6;
        const int c = n & 63;
        ushort4 pk;
        pk.x = f2bf(acc[mi][ni][0] + bv8[ni]);
        pk.y = f2bf(acc[mi][ni][1] + bv8[ni]);
        pk.z = f2bf(acc[mi][ni][2] + bv8[ni]);
        pk.w = f2bf(acc[mi][ni][3] + bv8[ni]);
        *(ushort4*)(VtO + (((size_t)b * NH + h) * DK + c) * S_LEN + s) = pk;
      }
  }
}

// ---------------------------------------------------------------------------
// Output GEMM: X = Obf @ Wot^T + bo + R (fp32 out). 128x128 tile,
// gload_lds staging. Frozen from R6.
// ---------------------------------------------------------------------------
__global__ __launch_bounds__(256) void gemm_out_kern(
    const ushort* __restrict__ A, const ushort* __restrict__ Wt,
    const float* __restrict__ bias, const float* __restrict__ R,
    float* __restrict__ X)
{
  __shared__ __align__(16) ushort Bl[2][128][64];  // 32 KB

  const int t = threadIdx.x;
  const int w = t >> 6;
  const int lane = t & 63;
  const int quad = lane >> 4;
  const int i16 = lane & 15;
  const int mbase = blockIdx.x * 128 + w * 32;
  const int nbase = blockIdx.y * 128;
  const int xb = i16 & 7;

  const int srow = t >> 3;
  const int lcg = (t & 7) ^ (srow & 7);
  const ushort* Bsrc = Wt + (size_t)(nbase + srow) * 512 + lcg * 8;
  char* const lw = (char*)&Bl[0][0][0] + w * 1024;

  const ushort* Ap = A + (size_t)(mbase + i16) * 512 + quad * 8;

  floatx4 acc[2][8];
#pragma unroll
  for (int mi = 0; mi < 2; ++mi)
#pragma unroll
    for (int ni = 0; ni < 8; ++ni) acc[mi][ni] = (floatx4)(0.f);

  short8 areg[2][2][2];
#pragma unroll
  for (int mi = 0; mi < 2; ++mi)
#pragma unroll
    for (int kc = 0; kc < 2; ++kc)
      areg[0][mi][kc] = *(const short8*)(Ap + kc * 32 + mi * 16 * 512);

#pragma unroll
  for (int c = 0; c < 4; ++c)
    gload16(Bsrc + (size_t)c * 16384, lw + c * 4096);
  __syncthreads();

#pragma unroll
  for (int kt = 0; kt < 8; ++kt) {
    const int cb = kt & 1;
    if (kt < 7) {
#pragma unroll
      for (int c = 0; c < 4; ++c)
        gload16(Bsrc + (size_t)c * 16384 + (kt + 1) * 64,
                lw + (cb ^ 1) * 16384 + c * 4096);
#pragma unroll
      for (int mi = 0; mi < 2; ++mi)
#pragma unroll
        for (int kc = 0; kc < 2; ++kc)
          areg[(kt + 1) & 1][mi][kc] =
              *(const short8*)(Ap + (kt + 1) * 64 + kc * 32 + mi * 16 * 512);
    }
#pragma unroll
    for (int kc = 0; kc < 2; ++kc) {
      short8 bf8[8];
#pragma unroll
      for (int ni = 0; ni < 8; ++ni)
        bf8[ni] = *(const short8*)&Bl[cb][ni * 16 + i16][((kc * 4 + quad) ^ xb) * 8];
#pragma unroll
      for (int mi = 0; mi < 2; ++mi)
#pragma unroll
        for (int ni = 0; ni < 8; ++ni)
          acc[mi][ni] = __builtin_amdgcn_mfma_f32_16x16x32_bf16(
              areg[kt & 1][mi][kc], bf8[ni], acc[mi][ni], 0, 0, 0);
    }
    if (kt < 7) __syncthreads();
  }

  float bv8[8];
#pragma unroll
  for (int ni = 0; ni < 8; ++ni) bv8[ni] = bias[nbase + ni * 16 + i16];
#pragma unroll
  for (int mi = 0; mi < 2; ++mi)
#pragma unroll
    for (int ni = 0; ni < 8; ++ni)
#pragma unroll
      for (int r = 0; r < 4; ++r) {
        const int m = mbase + mi * 16 + quad * 4 + r;
        const int n = nbase + ni * 16 + i16;
        X[(size_t)m * 512 + n] = acc[mi][ni][r] + bv8[ni] + R[(size_t)m * 512 + n];
      }
}

// ---------------------------------------------------------------------------
// MFMA dual-score causal attention. R7 DMA staging kept. R8: score scales
// baked out of the inner loop — c1 pre-applied to Qbf (GEMM epilogue), c2
// (per-head) applied to Qr ONCE per seg at load (unpack-scale-repack; qr
// buffer itself cannot be pre-scaled: it is also the z==0 GEMM's A input).
// Inner combine collapses to select+add. Everything else identical to R7.
// ---------------------------------------------------------------------------
__global__ __launch_bounds__(256) void attn_kern(
    const ushort* __restrict__ Qb, const ushort* __restrict__ Kb,
    const ushort* __restrict__ VtG, const ushort* __restrict__ qraw,
    const ushort* __restrict__ kraw,
    const unsigned long long* __restrict__ mbits,
    const float* __restrict__ gammas, ushort* __restrict__ Obf)
{
  __shared__ __align__(16) ushort Kp[2][64][64];
  __shared__ __align__(16) ushort Kr[2][64][64];
  __shared__ __align__(16) ushort Vc[2][64][64];
  __shared__ __align__(16) ushort Pl[4][16][64];

  const int t = threadIdx.x;
  const int w = t >> 6;
  const int lane = t & 63;
  const int quad = lane >> 4;
  const int i16 = lane & 15;
  const int bh = blockIdx.x;          // 0..63
  const int b = bh >> 3;
  const int h = bh & 7;
  const int p = blockIdx.y;           // 0..7

  const float gam = gammas[h];
  float te = __expf(-log1pf(__expf(gam)));
  te = fminf(fmaxf(te, 1e-5f), 1e5f);
  const float c2 = te * 0.044194173824159216f * 1.44269504f;

  const int xi = i16 & 7;
  const int rr = t >> 3;                  // staging row 0..31 (w*8 + lane>>3)
  const int lcs = (t & 7) ^ (rr & 7);     // pre-swizzled source chunk

  const ushort* kpgB = Kb + ((size_t)b * S_LEN + rr) * D_MOD + h * DK + lcs * 8;
  const ushort* krgB = kraw + ((size_t)b * S_LEN + rr) * D_MOD + h * DK + lcs * 8;
  const ushort* vgB  = VtG + ((size_t)bh * DK + rr) * S_LEN + lcs * 8;

  const int wr = w * 8;

#pragma unroll
  for (int seg = 0; seg < 2; ++seg) {
    const int qt = seg ? (15 - p) : p;
    const int qbase = qt * 64 + w * 16;

    short8 Qp[2], Qr[2];
    {
      const ushort* qp = Qb + ((size_t)b * S_LEN + qbase + i16) * D_MOD + h * DK + quad * 8;
      const ushort* qq = qraw + ((size_t)b * S_LEN + qbase + i16) * D_MOD + h * DK + quad * 8;
#pragma unroll
      for (int s = 0; s < 2; ++s) {
        Qp[s] = *(const short8*)(qp + s * 32);
        Qr[s] = *(const short8*)(qq + s * 32);
      }
      // bake per-head c2 into Qr once per seg (MFMA linear in A)
#pragma unroll
      for (int s = 0; s < 2; ++s) {
        U8 u; u.v = Qr[s];
#pragma unroll
        for (int j = 0; j < 8; ++j) {
          const float f = __uint_as_float((unsigned)u.u[j] << 16) * c2;
          u.u[j] = f2bf(f);
        }
        Qr[s] = u.v;
      }
    }

    floatx4 Oacc[4];
#pragma unroll
    for (int t4 = 0; t4 < 4; ++t4) Oacc[t4] = (floatx4)(0.f);
    float l_run[4] = {0.f, 0.f, 0.f, 0.f};

    const int nit = qt + 1;

    // ---- prologue: DMA tile 0 into buffer 0 ----
    __syncthreads();   // prior seg's readers done before overwrite
    gload16(kpgB, (char*)&Kp[0][wr][0]);
    gload16(kpgB + 32 * D_MOD, (char*)&Kp[0][32 + wr][0]);
    gload16(krgB, (char*)&Kr[0][wr][0]);
    gload16(krgB + 32 * D_MOD, (char*)&Kr[0][32 + wr][0]);
    gload16(vgB, (char*)&Vc[0][wr][0]);
    gload16(vgB + 32 * S_LEN, (char*)&Vc[0][32 + wr][0]);
    __syncthreads();   // vmcnt(0): tile 0 landed

    for (int kt = 0; kt < nit; ++kt) {
      const int cb = kt & 1;
      const int nb = cb ^ 1;
      const bool havenext = (kt + 1 < nit);
      const bool diag = (kt == qt);

      // ---- DMA next tile into the other buffer; lands during compute ----
      if (havenext) {
        const size_t ko = (size_t)(kt + 1) * 64;
        gload16(kpgB + ko * D_MOD, (char*)&Kp[nb][wr][0]);
        gload16(kpgB + ko * D_MOD + 32 * D_MOD, (char*)&Kp[nb][32 + wr][0]);
        gload16(krgB + ko * D_MOD, (char*)&Kr[nb][wr][0]);
        gload16(krgB + ko * D_MOD + 32 * D_MOD, (char*)&Kr[nb][32 + wr][0]);
        gload16(vgB + ko, (char*)&Vc[nb][wr][0]);
        gload16(vgB + ko + 32 * S_LEN, (char*)&Vc[nb][32 + wr][0]);
      }

      unsigned long long mw[4];
#pragma unroll
      for (int r = 0; r < 4; ++r)
        mw[r] = mbits[((size_t)b * S_LEN + qbase + quad * 4 + r) * 16 + kt];

      // ---- scores: 16 MFMAs from LDS ----
      floatx4 accp[4], accr[4];
#pragma unroll
      for (int t4 = 0; t4 < 4; ++t4) { accp[t4] = (floatx4)(0.f); accr[t4] = (floatx4)(0.f); }
#pragma unroll
      for (int s = 0; s < 2; ++s) {
        const int co = ((s * 4 + quad) ^ xi) * 8;
        short8 kp4[4], kr4[4];
#pragma unroll
        for (int t4 = 0; t4 < 4; ++t4) kp4[t4] = *(const short8*)&Kp[cb][t4 * 16 + i16][co];
#pragma unroll
        for (int t4 = 0; t4 < 4; ++t4) kr4[t4] = *(const short8*)&Kr[cb][t4 * 16 + i16][co];
#pragma unroll
        for (int t4 = 0; t4 < 4; ++t4)
          accp[t4] = __builtin_amdgcn_mfma_f32_16x16x32_bf16(Qp[s], kp4[t4], accp[t4], 0, 0, 0);
#pragma unroll
        for (int t4 = 0; t4 < 4; ++t4)
          accr[t4] = __builtin_amdgcn_mfma_f32_16x16x32_bf16(Qr[s], kr4[t4], accr[t4], 0, 0, 0);
      }

      // ---- combine (select+add) + exp2, P -> per-wave LDS ----
      const int k0g = kt * 64;
#pragma unroll
      for (int r = 0; r < 4; ++r) {
        const int qg = qbase + quad * 4 + r;
        const int prow = quad * 4 + r;
#pragma unroll
        for (int t4 = 0; t4 < 4; ++t4) {
          const float add = ((mw[r] >> (t4 * 16 + i16)) & 1ULL) ? accr[t4][r] : 0.f;
          const float sv = accp[t4][r] + add;
          float pv = __builtin_amdgcn_exp2f(sv);
          if (diag) {
            const int kg = k0g + t4 * 16 + i16;
            pv = (kg < qg) ? pv : 0.f;
          }
          l_run[r] += pv;
          const int kc = t4 * 2 + (i16 >> 3);
          Pl[w][prow][((kc ^ (prow & 7)) * 8) + (i16 & 7)] =
              (ushort)(__float_as_uint(pv) >> 16);
        }
      }

      // ---- PV: 8 MFMAs ----
#pragma unroll
      for (int s = 0; s < 2; ++s) {
        const int co = ((s * 4 + quad) ^ xi) * 8;
        short8 a = *(const short8*)&Pl[w][i16][co];
#pragma unroll
        for (int t4 = 0; t4 < 4; ++t4) {
          short8 bv8 = *(const short8*)&Vc[cb][t4 * 16 + i16][co];
          Oacc[t4] = __builtin_amdgcn_mfma_f32_16x16x32_bf16(a, bv8, Oacc[t4], 0, 0, 0);
        }
      }

      // ---- barrier: drains next-tile DMA, fences buffer reuse ----
      if (havenext) __syncthreads();
    }

    // ---- epilogue ----
#pragma unroll
    for (int r = 0; r < 4; ++r) {
      float l = l_run[r];
#pragma unroll
      for (int off = 1; off < 16; off <<= 1) l += __shfl_xor(l, off);
      const float inv = (l > 0.f) ? 1.f / l : 0.f;
      ushort* orow = Obf + ((size_t)b * S_LEN + qbase + quad * 4 + r) * D_MOD + h * DK;
#pragma unroll
      for (int t4 = 0; t4 < 4; ++t4)
        orow[t4 * 16 + i16] = f2bf(Oacc[t4][r] * inv);
    }
  }
}

// ---------------------------------------------------------------------------
// LayerNorm over D=512, one wave per row.
// ---------------------------------------------------------------------------
__global__ __launch_bounds__(256) void ln_kern(
    const float* __restrict__ X, const float* __restrict__ gw,
    const float* __restrict__ bw, float* __restrict__ out)
{
  const int row = blockIdx.x * 4 + (threadIdx.x >> 6);
  const int lane = threadIdx.x & 63;
  const int c = lane * 8;
  const float* xp = &X[(size_t)row * D_MOD + c];
  const float4 x0 = *(const float4*)xp;
  const float4 x1 = *(const float4*)(xp + 4);
  float xv[8] = {x0.x, x0.y, x0.z, x0.w, x1.x, x1.y, x1.z, x1.w};
  float sum = 0.f;
#pragma unroll
  for (int u = 0; u < 8; ++u) sum += xv[u];
#pragma unroll
  for (int off = 1; off < 64; off <<= 1) sum += __shfl_xor(sum, off, 64);
  const float mu = sum * (1.f / 512.f);
  float ss = 0.f;
#pragma unroll
  for (int u = 0; u < 8; ++u) { xv[u] -= mu; ss += xv[u] * xv[u]; }
#pragma unroll
  for (int off = 1; off < 64; off <<= 1) ss += __shfl_xor(ss, off, 64);
  const float rstd = rsqrtf(ss * (1.f / 512.f) + 1e-5f);
  const float4 g0 = *(const float4*)&gw[c];
  const float4 g1 = *(const float4*)&gw[c + 4];
  const float4 b0 = *(const float4*)&bw[c];
  const float4 b1 = *(const float4*)&bw[c + 4];
  float* op = &out[(size_t)row * D_MOD + c];
  *(float4*)op = make_float4(xv[0] * rstd * g0.x + b0.x,
                             xv[1] * rstd * g0.y + b0.y,
                             xv[2] * rstd * g0.z + b0.z,
                             xv[3] * rstd * g0.w + b0.w);
  *(float4*)(op + 4) = make_float4(xv[4] * rstd * g1.x + b1.x,
                                   xv[5] * rstd * g1.y + b1.y,
                                   xv[6] * rstd * g1.z + b1.z,
                                   xv[7] * rstd * g1.w + b1.w);
}

// ---------------------------------------------------------------------------
extern "C" void kernel_launch(void* const* d_in, const int* in_sizes, int n_in,
                              void* d_out, int out_size, void* d_ws, size_t ws_size,
                              hipStream_t stream)
{
  const float* q_in  = (const float*)d_in[0];
  const float* k_in  = (const float*)d_in[1];
  const float* v_in  = (const float*)d_in[2];
  const int*   smask = (const int*)d_in[3];
  const float* Wq = (const float*)d_in[4];
  const float* bq = (const float*)d_in[5];
  const float* Wv = (const float*)d_in[6];
  const float* bv = (const float*)d_in[7];
  const float* Wo = (const float*)d_in[8];
  const float* bo = (const float*)d_in[9];
  const float* gammas = (const float*)d_in[10];
  const float* ln_g = (const float*)d_in[11];
  const float* ln_b = (const float*)d_in[12];
  float* out = (float*)d_out;

  char* ws = (char*)d_ws;
  const size_t BF = (size_t)NB * S_LEN * D_MOD * sizeof(ushort);  // 8 MiB
  ushort* qr  = (ushort*)(ws);                 // [0,8M)
  ushort* kr  = (ushort*)(ws + BF);            // [8M,16M)
  ushort* vr  = (ushort*)(ws + 2 * BF);        // [16M,24M); Obf overlays after V-GEMM
  ushort* Obf = (ushort*)(ws + 2 * BF);
  ushort* Qbf = (ushort*)(ws + 3 * BF);        // [24M,32M)
  ushort* Kbf = (ushort*)(ws + 4 * BF);        // [32M,40M)
  ushort* Vt  = (ushort*)(ws + 5 * BF);        // [40M,48M)
  unsigned long long* mbits = (unsigned long long*)(ws + 6 * BF);      // 1 MiB
  ushort* Wqt = (ushort*)(ws + 6 * BF + (1 << 20));                    // 512 KiB
  ushort* Wvt = Wqt + 512 * 512;
  ushort* Wot = Wvt + 512 * 512;
  float*  X   = (float*)ws;                    // overlays qr+kr (dead after attn)

  const dim3 tb(256);

  prep_kern<<<dim3(2048, 5), tb, 0, stream>>>(q_in, k_in, v_in, smask,
                                              Wq, Wv, Wo,
                                              qr, kr, vr, mbits,
                                              Wqt, Wvt, Wot);

  gemm_qkv_kern<<<dim3(64, 4, 3), tb, 0, stream>>>(qr, kr, vr, Wqt, Wvt,
                                                   bq, bv, Qbf, Kbf, Vt);

  attn_kern<<<dim3(64, 8), tb, 0, stream>>>(Qbf, Kbf, Vt, qr, kr, mbits,
                                            gammas, Obf);

  gemm_out_kern<<<dim3(64, 4), tb, 0, stream>>>(Obf, Wot, bo, q_in, X);
  ln_kern<<<2048, tb, 0, stream>>>(X, ln_g, ln_b, out);
}